// Round 11
// baseline (914.181 us; speedup 1.0000x reference)
//
#include <hip/hip_runtime.h>
#include <stdint.h>

#define BB      512
#define NCROPS  5
#define TT      8192
#define NT      256     // threads per block
#define NW      4       // waves per block
#define UPR     8       // 1024-elem units per row
#define HPAD    257     // 256 bins + 1 pad word

// Order-preserving f32 -> u32 transform (ascending).
// Every real float maps to a key > 0, so 0u is a safe "masked" sentinel.
__device__ __forceinline__ uint32_t f2ord(float f) {
    uint32_t b = __float_as_uint(f);
    return (b & 0x80000000u) ? ~b : (b | 0x80000000u);
}
__device__ __forceinline__ float ord2f(uint32_t u) {
    uint32_t b = (u & 0x80000000u) ? (u & 0x7FFFFFFFu) : ~u;
    return __uint_as_float(b);
}

#define FOR8(OP) OP(u0) OP(u1) OP(u2) OP(u3) OP(u4) OP(u5) OP(u6) OP(u7)

__global__ __launch_bounds__(NT) void chunk_topk(
    const float* __restrict__ scores, const int* __restrict__ label,
    const int* __restrict__ seqlen, uint32_t* __restrict__ keys,
    uint32_t* __restrict__ row_done, uint32_t* __restrict__ all_done,
    float* __restrict__ row_loss, float* __restrict__ out)
{
    const int tid  = threadIdx.x;
    const int lane = tid & 63;
    const int wave = tid >> 6;
    const int unit = (int)blockIdx.x;
    const int r    = unit >> 3;
    const int c    = unit & 7;
    const int sl   = seqlen[r];
    const int nunits = (sl + 1023) >> 10;       // >= 1 since sl >= 16
    if (c >= nunits) return;                    // whole unit beyond seqlen

    // ---- Phase A: stream this unit (crop-mean + mask -> order keys) ----
    const int t0 = (c << 10) + (tid << 2);
    if (t0 < sl) {
        const float* base = scores + (size_t)r * (NCROPS * TT) + t0;
        float4 a        = *reinterpret_cast<const float4*>(base);
        const float4 v1 = *reinterpret_cast<const float4*>(base + 1 * TT);
        const float4 v2 = *reinterpret_cast<const float4*>(base + 2 * TT);
        const float4 v3 = *reinterpret_cast<const float4*>(base + 3 * TT);
        const float4 v4 = *reinterpret_cast<const float4*>(base + 4 * TT);
        a.x = (a.x + v1.x + v2.x + v3.x + v4.x) * 0.2f;
        a.y = (a.y + v1.y + v2.y + v3.y + v4.y) * 0.2f;
        a.z = (a.z + v1.z + v2.z + v3.z + v4.z) * 0.2f;
        a.w = (a.w + v1.w + v2.w + v3.w + v4.w) * 0.2f;
        uint4 kv;
        kv.x = f2ord(a.x);                       // t0 < sl guaranteed
        kv.y = (t0 + 1 < sl) ? f2ord(a.y) : 0u;
        kv.z = (t0 + 2 < sl) ? f2ord(a.z) : 0u;
        kv.w = (t0 + 3 < sl) ? f2ord(a.w) : 0u;
        *reinterpret_cast<uint4*>(keys + (size_t)r * TT + t0) = kv;
    }

    // ---- completion protocol: last unit-block of the row runs the select ----
    __threadfence();                             // release our key writes
    __syncthreads();
    __shared__ int s_go;
    if (tid == 0)
        s_go = (atomicAdd(&row_done[r], 1u) == (uint32_t)(nunits - 1));
    __syncthreads();
    if (!s_go) return;
    __threadfence();                             // acquire all units' keys

    // ---- Phase B: per-row k-th-largest select + BCE term ----
    const int lb = label[r];
    const int k  = (lb == 0) ? 1 : (sl / 16 + 1);   // 1 <= k <= sl

    __shared__ uint32_t hist[2][NW][HPAD];       // ~8.3 KB double-buffered
    __shared__ uint32_t bc_p, bc_k;
    __shared__ uint32_t s_m[NW];
    __shared__ float    s_s[NW];
    __shared__ int      s_c[NW];

    const uint32_t* kbase = keys + (size_t)r * TT;
    uint4 u0, u1, u2, u3, u4, u5, u6, u7;
    #define KL(DST, J) { \
        const int t4 = tid + (J) * NT; \
        if (4 * t4 < sl) DST = *reinterpret_cast<const uint4*>(kbase + 4 * t4); \
        else { DST.x = 0u; DST.y = 0u; DST.z = 0u; DST.w = 0u; } }
    KL(u0, 0) KL(u1, 1) KL(u2, 2) KL(u3, 3)
    KL(u4, 4) KL(u5, 5) KL(u6, 6) KL(u7, 7)

    {   // zero histogram buffer 0 while key loads are in flight
        uint32_t* hz = &hist[0][0][0];
        for (int i = tid; i < NW * HPAD; i += NT) hz[i] = 0u;
    }
    __syncthreads();

    uint32_t thr;
    if (k == 1) {
        // label==0 fast path: threshold = row max
        uint32_t mx = 0u;
        #define MAXOP(V) mx = max(mx, max(max(V.x, V.y), max(V.z, V.w)));
        FOR8(MAXOP)
        #pragma unroll
        for (int off = 32; off; off >>= 1) {
            const uint32_t o = (uint32_t)__shfl_down((int)mx, off);
            mx = max(mx, o);
        }
        if (lane == 0) s_m[wave] = mx;
        __syncthreads();
        uint32_t rowmax = s_m[0];
        #pragma unroll
        for (int w = 1; w < NW; ++w) rowmax = max(rowmax, s_m[w]);
        thr = rowmax;
    } else {
        // MSB-first radix select, 4 rounds x 8 bits
        uint32_t p = 0u, kr = (uint32_t)k;
        #pragma unroll
        for (int rr = 0; rr < 4; ++rr) {
            uint32_t* h = &hist[rr & 1][wave][0];
            if (rr == 0) {
                #define H0(X)  if ((X) != 0u) atomicAdd(&h[(X) >> 24], 1u);
                #define H0V(V) H0(V.x) H0(V.y) H0(V.z) H0(V.w)
                FOR8(H0V)
            } else {
                const int shp = 32 - 8 * rr;  // prefix shift
                const int shd = shp - 8;      // digit shift
                #define HR(X)  if ((X) != 0u && ((X) >> shp) == p) atomicAdd(&h[((X) >> shd) & 255u], 1u);
                #define HRV(V) HR(V.x) HR(V.y) HR(V.z) HR(V.w)
                FOR8(HRV)
            }
            __syncthreads();
            if (wave == 0) {
                // combine 4 wave-hists (4 bins/lane), suffix-scan, pick digit
                uint32_t t0s = 0u, t1s = 0u, t2s = 0u, t3s = 0u;
                #pragma unroll
                for (int w = 0; w < NW; ++w) {
                    const uint32_t* hw = &hist[rr & 1][w][0];
                    t0s += hw[4 * lane + 0];
                    t1s += hw[4 * lane + 1];
                    t2s += hw[4 * lane + 2];
                    t3s += hw[4 * lane + 3];
                }
                const uint32_t s = t0s + t1s + t2s + t3s;
                uint32_t suf = s;                         // inclusive suffix sum
                #pragma unroll
                for (int off = 1; off < 64; off <<= 1) {
                    const uint32_t v = (uint32_t)__shfl_down((int)suf, off);
                    if (lane + off < 64) suf += v;
                }
                const uint32_t E  = suf - s;              // sum over lanes > l
                const uint32_t T3 = E  + t3s;             // T(c)=cnt(keys>=bin c)
                const uint32_t T2 = T3 + t2s;
                const uint32_t T1 = T2 + t1s;
                const uint32_t T0 = T1 + t0s;
                const unsigned long long bal = __ballot(T0 >= kr);
                const int L = 63 - __clzll(bal);          // highest lane, T0 >= kr
                if (lane == L) {
                    uint32_t j, Tj, tj;
                    if      (T3 >= kr) { j = 3u; Tj = T3; tj = t3s; }
                    else if (T2 >= kr) { j = 2u; Tj = T2; tj = t2s; }
                    else if (T1 >= kr) { j = 1u; Tj = T1; tj = t1s; }
                    else               { j = 0u; Tj = T0; tj = t0s; }
                    bc_p = (p << 8) | (uint32_t)(4 * lane) | j;
                    bc_k = kr - (Tj - tj);                // rank within chosen bin
                }
            } else {
                // zero the other buffer (overlaps the scan); waves 1..3
                uint32_t* hz = &hist[(rr + 1) & 1][0][0];
                for (int i = tid - 64; i < NW * HPAD; i += (NT - 64)) hz[i] = 0u;
            }
            __syncthreads();
            p  = bc_p;
            kr = bc_k;
        }
        thr = p;   // exact bit pattern of the k-th largest key
    }

    // unified epilogue: topk = sum(u>=thr) - (cnt(u>=thr)-k)*val(thr)
    float sg = 0.f;
    int   cg = 0;
    #define SUMOP(V) \
        if (V.x >= thr) { sg += ord2f(V.x); cg++; } \
        if (V.y >= thr) { sg += ord2f(V.y); cg++; } \
        if (V.z >= thr) { sg += ord2f(V.z); cg++; } \
        if (V.w >= thr) { sg += ord2f(V.w); cg++; }
    FOR8(SUMOP)
    #pragma unroll
    for (int off = 32; off; off >>= 1) {
        sg += __shfl_down(sg, off);
        cg += __shfl_down(cg, off);
    }
    if (lane == 0) { s_s[wave] = sg; s_c[wave] = cg; }
    __syncthreads();

    if (tid == 0) {
        float S = 0.f; int C = 0;
        #pragma unroll
        for (int w = 0; w < NW; ++w) { S += s_s[w]; C += s_c[w]; }
        const float kf   = ord2f(thr);
        const float topk = S - (float)(C - k) * kf;
        const float v    = topk / (float)k;
        const float y    = (float)lb;
        const float la   = fmaxf(v, 0.f) + log1pf(expf(-fabsf(v)));  // logaddexp(0,v)
        row_loss[r] = la - v * y;
    }

    // ---- Phase C: last completed row's block does the final reduce ----
    __threadfence();
    __syncthreads();
    if (tid == 0)
        s_go = (atomicAdd(all_done, 1u) == (uint32_t)(BB - 1));
    __syncthreads();
    if (!s_go) return;
    __threadfence();                             // acquire all row_loss writes

    float v = row_loss[tid] + row_loss[tid + NT];
    #pragma unroll
    for (int off = 32; off; off >>= 1) v += __shfl_down(v, off);
    if (lane == 0) s_s[wave] = v;
    __syncthreads();
    if (tid == 0) {
        float S = 0.f;
        #pragma unroll
        for (int w = 0; w < NW; ++w) S += s_s[w];
        out[0] = S * (1.0f / (float)BB);
    }
}

extern "C" void kernel_launch(void* const* d_in, const int* in_sizes, int n_in,
                              void* d_out, int out_size, void* d_ws, size_t ws_size,
                              hipStream_t stream) {
    const float* scores = (const float*)d_in[0];
    const int*   label  = (const int*)d_in[1];
    const int*   seqlen = (const int*)d_in[2];
    float* out = (float*)d_out;

    const size_t keys_bytes = (size_t)BB * TT * sizeof(uint32_t);   // 16.8 MB
    uint32_t* keys     = (uint32_t*)d_ws;
    float*    row_loss = (float*)((char*)d_ws + keys_bytes);        // 512 floats
    uint32_t* row_done = (uint32_t*)((char*)d_ws + keys_bytes + 2048);  // 512 u32
    uint32_t* all_done = row_done + BB;                                  // 1 u32

    hipMemsetAsync(row_done, 0, (BB + 1) * sizeof(uint32_t), stream);
    chunk_topk<<<BB * UPR, NT, 0, stream>>>(scores, label, seqlen, keys,
                                            row_done, all_done, row_loss, out);
}

// Round 12
// 36.461 us; speedup vs baseline: 25.0727x; 25.0727x over previous
//
#include <hip/hip_runtime.h>
#include <stdint.h>

#define BB      512
#define NCROPS  5
#define TT      8192
#define THREADS 512
#define WAVES   8
#define NBLK    256     // persistent blocks, 1 per CU; must be < BB for queue slack
#define HPAD    257     // 256 bins + 1 pad word

// Order-preserving f32 -> u32 transform (ascending).
// Every real float maps to a key > 0, so 0u is a safe "masked" sentinel.
__device__ __forceinline__ uint32_t f2ord(float f) {
    uint32_t b = __float_as_uint(f);
    return (b & 0x80000000u) ? ~b : (b | 0x80000000u);
}
__device__ __forceinline__ float ord2f(uint32_t u) {
    uint32_t b = (u & 0x80000000u) ? (u & 0x7FFFFFFFu) : ~u;
    return __uint_as_float(b);
}

#define FOR4(OP) OP(u0) OP(u1) OP(u2) OP(u3)

// issue 5 predicated crop loads for group J of row ROW (floats land in A..E)
#define ISSUE1(BASE, SL, A,B,C,D,E, J) \
    if (4 * (tid + (J) * THREADS) < (SL)) { \
        const float* bp_ = (BASE) + 4 * (tid + (J) * THREADS); \
        A = *reinterpret_cast<const float4*>(bp_); \
        B = *reinterpret_cast<const float4*>(bp_ + 1 * TT); \
        C = *reinterpret_cast<const float4*>(bp_ + 2 * TT); \
        D = *reinterpret_cast<const float4*>(bp_ + 3 * TT); \
        E = *reinterpret_cast<const float4*>(bp_ + 4 * TT); \
    }

#define ISSUE(ROW, SL) { \
    const float* base_ = scores + (size_t)(ROW) * (NCROPS * TT); \
    ISSUE1(base_, SL, a0,a1,a2,a3,a4, 0) \
    ISSUE1(base_, SL, b0,b1,b2,b3,b4, 1) \
    ISSUE1(base_, SL, c0,c1,c2,c3,c4, 2) \
    ISSUE1(base_, SL, d0,d1,d2,d3,d4, 3) }

#define KEY1(DST, SL, A,B,C,D,E, J) \
    if (4 * (tid + (J) * THREADS) < (SL)) { \
        const int t0_ = 4 * (tid + (J) * THREADS); \
        float4 m_; \
        m_.x = (A.x + B.x + C.x + D.x + E.x) * 0.2f; \
        m_.y = (A.y + B.y + C.y + D.y + E.y) * 0.2f; \
        m_.z = (A.z + B.z + C.z + D.z + E.z) * 0.2f; \
        m_.w = (A.w + B.w + C.w + D.w + E.w) * 0.2f; \
        DST.x = f2ord(m_.x); \
        DST.y = (t0_ + 1 < (SL)) ? f2ord(m_.y) : 0u; \
        DST.z = (t0_ + 2 < (SL)) ? f2ord(m_.z) : 0u; \
        DST.w = (t0_ + 3 < (SL)) ? f2ord(m_.w) : 0u; \
    } else { DST.x = 0u; DST.y = 0u; DST.z = 0u; DST.w = 0u; }

#define KEYS(SL) \
    KEY1(u0, SL, a0,a1,a2,a3,a4, 0) \
    KEY1(u1, SL, b0,b1,b2,b3,b4, 1) \
    KEY1(u2, SL, c0,c1,c2,c3,c4, 2) \
    KEY1(u3, SL, d0,d1,d2,d3,d4, 3)

#define MAXOP(V) mx = max(mx, max(max(V.x, V.y), max(V.z, V.w)));
#define H0(X)    if ((X) != 0u) atomicAdd(&h[(X) >> 24], 1u);
#define H0V(V)   H0(V.x) H0(V.y) H0(V.z) H0(V.w)
#define HR(X)    if ((X) != 0u && ((X) >> shp) == p) atomicAdd(&h[((X) >> shd) & 255u], 1u);
#define HRV(V)   HR(V.x) HR(V.y) HR(V.z) HR(V.w)

// k-th largest key of {u0..u3} across the block -> THR.
// Entry invariant: hist[0] zeroed. Exit invariant: hist[0] zeroed (radix path
// re-zeroes at r=3; k==1 path never dirties it).
#define SELECT(THR, KK) { \
    if ((KK) == 1) { \
        uint32_t mx = 0u; \
        FOR4(MAXOP) \
        for (int off = 32; off; off >>= 1) { \
            const uint32_t o = (uint32_t)__shfl_down((int)mx, off); \
            mx = max(mx, o); \
        } \
        if (lane == 0) s_m[wave] = mx; \
        __syncthreads(); \
        uint32_t rowmax = s_m[0]; \
        for (int w = 1; w < WAVES; ++w) rowmax = max(rowmax, s_m[w]); \
        THR = rowmax; \
    } else { \
        uint32_t p = 0u, kr = (uint32_t)(KK); \
        for (int r = 0; r < 4; ++r) { \
            uint32_t* h = &hist[r & 1][wave][0]; \
            if (r == 0) { FOR4(H0V) } \
            else { \
                const int shp = 32 - 8 * r; \
                const int shd = shp - 8; \
                FOR4(HRV) \
            } \
            __syncthreads(); \
            if (wave == 0) { \
                uint32_t t0s = 0u, t1s = 0u, t2s = 0u, t3s = 0u; \
                for (int w = 0; w < WAVES; ++w) { \
                    const uint32_t* hw = &hist[r & 1][w][0]; \
                    t0s += hw[4 * lane + 0]; \
                    t1s += hw[4 * lane + 1]; \
                    t2s += hw[4 * lane + 2]; \
                    t3s += hw[4 * lane + 3]; \
                } \
                const uint32_t s = t0s + t1s + t2s + t3s; \
                uint32_t suf = s; \
                for (int off = 1; off < 64; off <<= 1) { \
                    const uint32_t v = (uint32_t)__shfl_down((int)suf, off); \
                    if (lane + off < 64) suf += v; \
                } \
                const uint32_t E  = suf - s; \
                const uint32_t T3 = E  + t3s; \
                const uint32_t T2 = T3 + t2s; \
                const uint32_t T1 = T2 + t1s; \
                const uint32_t T0 = T1 + t0s; \
                const unsigned long long bal = __ballot(T0 >= kr); \
                const int L = 63 - __clzll(bal); \
                if (lane == L) { \
                    uint32_t j, Tj, tj; \
                    if      (T3 >= kr) { j = 3u; Tj = T3; tj = t3s; } \
                    else if (T2 >= kr) { j = 2u; Tj = T2; tj = t2s; } \
                    else if (T1 >= kr) { j = 1u; Tj = T1; tj = t1s; } \
                    else               { j = 0u; Tj = T0; tj = t0s; } \
                    bc_p = (p << 8) | (uint32_t)(4 * lane) | j; \
                    bc_k = kr - (Tj - tj); \
                } \
            } else { \
                uint32_t* hz = &hist[(r + 1) & 1][0][0]; \
                for (int i = tid - 64; i < WAVES * HPAD; i += (THREADS - 64)) hz[i] = 0u; \
            } \
            __syncthreads(); \
            p  = bc_p; \
            kr = bc_k; \
        } \
        THR = p; \
    } }

#define SUMOP(V) \
    if (V.x >= _thr) { sg += ord2f(V.x); cg++; } \
    if (V.y >= _thr) { sg += ord2f(V.y); cg++; } \
    if (V.z >= _thr) { sg += ord2f(V.z); cg++; } \
    if (V.w >= _thr) { sg += ord2f(V.w); cg++; }

#define EPILOGUE(THR, KK, LB, ROW) { \
    const uint32_t _thr = (THR); \
    float sg = 0.f; int cg = 0; \
    FOR4(SUMOP) \
    for (int off = 32; off; off >>= 1) { \
        sg += __shfl_down(sg, off); \
        cg += __shfl_down(cg, off); \
    } \
    if (lane == 0) { s_s[wave] = sg; s_c[wave] = cg; } \
    __syncthreads(); \
    if (tid == 0) { \
        float S = 0.f; int C = 0; \
        for (int w = 0; w < WAVES; ++w) { S += s_s[w]; C += s_c[w]; } \
        const float kf   = ord2f(_thr); \
        const float topk = S - (float)(C - (KK)) * kf; \
        const float v    = topk / (float)(KK); \
        const float y    = (float)(LB); \
        const float la   = fmaxf(v, 0.f) + log1pf(expf(-fabsf(v))); \
        row_loss[ROW] = la - v * y; \
    } \
    __syncthreads(); }

__global__ __launch_bounds__(THREADS, 2) void queue_topk(
    const float* __restrict__ scores, const int* __restrict__ label,
    const int* __restrict__ seqlen, float* __restrict__ row_loss,
    uint32_t* __restrict__ qctr, uint32_t* __restrict__ done,
    float* __restrict__ out)
{
    const int tid  = threadIdx.x;
    const int lane = tid & 63;
    const int wave = tid >> 6;

    __shared__ uint32_t hist[2][WAVES][HPAD];   // ~16.4 KB, double-buffered
    __shared__ uint32_t bc_p, bc_k;
    __shared__ uint32_t s_m[WAVES];
    __shared__ float    s_s[WAVES];
    __shared__ int      s_c[WAVES];
    __shared__ int      s_next;
    __shared__ int      s_go;

    // establish hist[0]-zeroed invariant
    {
        uint32_t* hz = &hist[0][0][0];
        for (int i = tid; i < WAVES * HPAD; i += THREADS) hz[i] = 0u;
    }

    float4 a0,a1,a2,a3,a4, b0,b1,b2,b3,b4, c0,c1,c2,c3,c4, d0,d1,d2,d3,d4;

    // first pop + issue
    __syncthreads();
    if (tid == 0) s_next = (int)atomicAdd(qctr, 1u);
    __syncthreads();
    int cur = s_next;
    int slc = 0;
    if (cur < BB) {
        slc = seqlen[cur];
        ISSUE(cur, slc)
    }

    while (cur < BB) {
        // keys for current row (drains its loads; raw floats die here)
        uint4 u0, u1, u2, u3;
        KEYS(slc)
        const int lb = label[cur];
        const int k  = (lb == 0) ? 1 : (slc / 16 + 1);   // 1 <= k <= slc

        // pop next row and issue its loads NOW -> stream under select(cur)
        __syncthreads();
        if (tid == 0) s_next = (int)atomicAdd(qctr, 1u);
        __syncthreads();
        const int nxt = s_next;
        int sln = 0;
        if (nxt < BB) {
            sln = seqlen[nxt];
            ISSUE(nxt, sln)
        }
        asm volatile("" ::: "memory");   // pin load issue before select

        uint32_t thr;
        SELECT(thr, k)
        EPILOGUE(thr, k, lb, cur)

        cur = nxt;
        slc = sln;
    }

    // ---- completion: one release fence per block, last block reduces ----
    if (tid == 0) {
        __threadfence();                 // release row_loss writes
        s_go = (atomicAdd(done, 1u) == (uint32_t)(NBLK - 1));
    }
    __syncthreads();
    if (s_go) {
        __threadfence();                 // acquire all blocks' row_loss
        float v = __hip_atomic_load(&row_loss[tid], __ATOMIC_RELAXED,
                                    __HIP_MEMORY_SCOPE_AGENT);
        #pragma unroll
        for (int off = 32; off; off >>= 1) v += __shfl_down(v, off);
        if (lane == 0) s_s[wave] = v;
        __syncthreads();
        if (tid == 0) {
            float S = 0.f;
            #pragma unroll
            for (int w = 0; w < WAVES; ++w) S += s_s[w];
            out[0] = S * (1.0f / (float)BB);
        }
    }
}

extern "C" void kernel_launch(void* const* d_in, const int* in_sizes, int n_in,
                              void* d_out, int out_size, void* d_ws, size_t ws_size,
                              hipStream_t stream) {
    const float* scores = (const float*)d_in[0];
    const int*   label  = (const int*)d_in[1];
    const int*   seqlen = (const int*)d_in[2];
    float* out = (float*)d_out;

    float*    row_loss = (float*)d_ws;                        // 512 floats
    uint32_t* qctr     = (uint32_t*)((char*)d_ws + 2048);     // queue counter
    uint32_t* done     = qctr + 1;                            // done counter

    hipMemsetAsync(qctr, 0, 2 * sizeof(uint32_t), stream);
    queue_topk<<<NBLK, THREADS, 0, stream>>>(scores, label, seqlen,
                                             row_loss, qctr, done, out);
}